// Round 7
// baseline (90.767 us; speedup 1.0000x reference)
//
#include <hip/hip_runtime.h>

// SSIM v19: v18 pipeline (4-slot / 3-lookahead reg staging, zero-shuffle
// vstep, BY=256) with COALESCED global loads + per-wave LDS bounce.
// Evidence R0-R6: load delivery pinned <=1.85 TB/s across TLP x2 (R1),
// -LDS ops (R2), ILP-depth x3 (R6) -> per-CU line-throughput cap on the
// scattered hload pattern (16 rows x 3 misaligned lines = 48 lines/instr).
// v19 lane map (r=lane>>2, j=lane&3), 3 loads/img over the ALIGNED 192B
// row window [tx0w-16, tx0w+32): each instr = 16 rows x ONE aligned 64B
// line (16 lines/instr, stream-equivalent). Staged regs -> 4KB/img LDS
// buffer (rotate swizzle (seg+row)&15, bank-balanced) -> fragment reads
// reproduce the exact floats the old hload gave -> bit-identical math
// (absmax must stay exactly 0.0078125).
//
// Layout identity (unchanged): V-MFMA B-frag k=lg*8+j, n=ln vs H D-frag
// row=lg*4+j, col=ln. B-row permutation k=lg*8+j <-> window row
// (j<4 ? lg*4+j : 12+lg*4+j) makes lane-local {Dp.x,Dp.y,Dc.x,Dc.y} the
// B-frag verbatim; permutation absorbed into whv: whv[k][n]=wt[wr(k)-n-3].

typedef __attribute__((ext_vector_type(8))) short bf16x8;
typedef __attribute__((ext_vector_type(4))) float f32x4;

constexpr int TX   = 64;             // block out-cols (4 waves x 16)
constexpr int BY   = 256;            // block out-rows
constexpr int IMW  = 512;
constexpr int IMH  = 512;
constexpr int NPL  = 48;
constexpr int GX   = IMW / TX;       // 8
constexpr int GYB  = IMH / BY;       // 2
constexpr int NBLK = GX * GYB * NPL; // 768
constexpr int NCH  = BY / 16;        // 16 chunk steps (chunks 0..16)
constexpr float C1c = 0.01f * 0.01f;
constexpr float C2c = 0.03f * 0.03f;

union frag {
    bf16x8 f;
    unsigned int u[4];
    uint4 q;
};

struct Chunk { float4 a0, a1, a2, b0, b1, b2; };   // 24 VGPR staging / slot

// RNE f32->bf16 pair pack (setup kernel only).
__device__ __forceinline__ unsigned int pk_bf16(float lo, float hi) {
    unsigned int a = __float_as_uint(lo);
    unsigned int b = __float_as_uint(hi);
    a += 0x7FFFu + ((a >> 16) & 1u);
    b += 0x7FFFu + ((b >> 16) & 1u);
    return (b & 0xFFFF0000u) | (a >> 16);
}

// Fast pack: round-half-up + byte-perm merge (3 VALU ops per pair).
__device__ __forceinline__ unsigned int pk_rhu(float lo, float hi, unsigned sel) {
    unsigned int a = __float_as_uint(lo) + 0x8000u;
    unsigned int b = __float_as_uint(hi) + 0x8000u;
    unsigned int r;
    asm("v_perm_b32 %0, %1, %2, %3" : "=v"(r) : "v"(b), "v"(a), "s"(sel));
    return r;
}

// Normalized 11-tap Gaussian (sigma=1.5); wt[d] for d in [0,11), else 0.
__device__ __forceinline__ float wsel(int d) {
    float w = 0.f;
    w = (d == 0 || d == 10) ? 0.00102838f : w;
    w = (d == 1 || d == 9)  ? 0.00759876f : w;
    w = (d == 2 || d == 8)  ? 0.03600077f : w;
    w = (d == 3 || d == 7)  ? 0.10936082f : w;
    w = (d == 4 || d == 6)  ? 0.21300553f : w;
    w = (d == 5)            ? 0.26601171f : w;
    return w;
}

// Per-lane weight fragments (8 words/lane):
//   words 0..3: whf  — H-pass B-frag,  W[k][n] = wt[k-n-3],   k = lg*8+j
//   words 4..7: whv  — V-pass A-frag with permuted rows,
//                      W'[k][n] = wt[wr(k)-n-3],
//                      wr(k) = (j<4 ? lg*4+j : 12+lg*4+j), j = k&7
__global__ void ssim_weight_setup(unsigned int* __restrict__ wbuf)
{
    const int lane = threadIdx.x & 63;
    const int ln   = lane & 15;
    const int lg   = lane >> 4;
#pragma unroll
    for (int w = 0; w < 4; ++w) {
        const int ka = lg * 8 + 2 * w;
        wbuf[lane * 8 + w] = pk_bf16(wsel(ka - ln - 3), wsel(ka + 1 - ln - 3));
        const int j0  = 2 * w;
        const int wr0 = (j0 < 4) ? (lg * 4 + j0) : (12 + lg * 4 + j0);
        wbuf[lane * 8 + 4 + w] = pk_bf16(wsel(wr0 - ln - 3), wsel(wr0 + 1 - ln - 3));
    }
}

// ---- forced-inline pipeline stages ----

__device__ __forceinline__ float4 gld(const float* __restrict__ row, int col, bool rowok)
{
    float4 v = make_float4(0.f, 0.f, 0.f, 0.f);
    if (rowok && ((unsigned)col <= (unsigned)(IMW - 4)))
        v = *reinterpret_cast<const float4*>(row + col);
    return v;
}

// Coalesced load of chunk c: lane (r=lane>>2, j=lane&3); 3 loads/img, each
// instr = 16 rows x one aligned 64B line of window [tx0w-16, tx0w+32).
__device__ __forceinline__ void hload(const float* __restrict__ p1,
                                      const float* __restrict__ p2,
                                      int y0, int r, int cA, int jj, int c,
                                      Chunk& ch)
{
    const int irow = y0 + 16 * c - 8 + r;
    const bool rowok = (unsigned)irow < (unsigned)IMH;
    const float* r1 = p1 + (size_t)irow * IMW;
    const float* r2 = p2 + (size_t)irow * IMW;
    const int c0 = cA + 4 * jj;          // float col of this lane's 16B seg, t=0
    ch.a0 = gld(r1, c0,      rowok);
    ch.a1 = gld(r1, c0 + 16, rowok);
    ch.a2 = gld(r1, c0 + 32, rowok);
    ch.b0 = gld(r2, c0,      rowok);
    ch.b1 = gld(r2, c0 + 16, rowok);
    ch.b2 = gld(r2, c0 + 32, rowok);
}

// Stage slot regs -> per-wave LDS buffer (rotate-swizzled row-major).
// img1 at [0,256) float4s, img2 at [256,512).
__device__ __forceinline__ void hstage(float4* __restrict__ ldsW,
                                       int wi0, int wi1, int wi2,
                                       const Chunk& ch)
{
    ldsW[wi0]       = ch.a0; ldsW[wi1]       = ch.a1; ldsW[wi2]       = ch.a2;
    ldsW[256 + wi0] = ch.b0; ldsW[256 + wi1] = ch.b1; ldsW[256 + wi2] = ch.b2;
}

// H-pass: read fragment floats from LDS (exactly the old hload values),
// pack, 5 MFMAs -> packed D (uint2 per plane).
__device__ __forceinline__ void hprocL(const frag& whf, unsigned sel,
                                       const float4* __restrict__ ldsW,
                                       int ri0, int ri1,
                                       uint2* __restrict__ D)
{
    const float4 ra0 = ldsW[ri0],       ra1 = ldsW[ri1];
    const float4 rb0 = ldsW[256 + ri0], rb1 = ldsW[256 + ri1];
    const float A[8] = {ra0.x, ra0.y, ra0.z, ra0.w, ra1.x, ra1.y, ra1.z, ra1.w};
    const float B[8] = {rb0.x, rb0.y, rb0.z, rb0.w, rb1.x, rb1.y, rb1.z, rb1.w};
    const f32x4 z = {0.f, 0.f, 0.f, 0.f};
    frag fa, fb, faa, fbb, fab;
#pragma unroll
    for (int w = 0; w < 4; ++w) {
        const float a0 = A[2*w], a1 = A[2*w+1];
        const float b0 = B[2*w], b1 = B[2*w+1];
        fa.u[w]  = pk_rhu(a0,      a1,      sel);
        fb.u[w]  = pk_rhu(b0,      b1,      sel);
        faa.u[w] = pk_rhu(a0 * a0, a1 * a1, sel);
        fbb.u[w] = pk_rhu(b0 * b0, b1 * b1, sel);
        fab.u[w] = pk_rhu(a0 * b0, a1 * b1, sel);
    }
    f32x4 d;
    d = __builtin_amdgcn_mfma_f32_16x16x32_bf16(fa.f,  whf.f, z, 0, 0, 0);
    D[0] = make_uint2(pk_rhu(d[0], d[1], sel), pk_rhu(d[2], d[3], sel));
    d = __builtin_amdgcn_mfma_f32_16x16x32_bf16(fb.f,  whf.f, z, 0, 0, 0);
    D[1] = make_uint2(pk_rhu(d[0], d[1], sel), pk_rhu(d[2], d[3], sel));
    d = __builtin_amdgcn_mfma_f32_16x16x32_bf16(faa.f, whf.f, z, 0, 0, 0);
    D[2] = make_uint2(pk_rhu(d[0], d[1], sel), pk_rhu(d[2], d[3], sel));
    d = __builtin_amdgcn_mfma_f32_16x16x32_bf16(fbb.f, whf.f, z, 0, 0, 0);
    D[3] = make_uint2(pk_rhu(d[0], d[1], sel), pk_rhu(d[2], d[3], sel));
    d = __builtin_amdgcn_mfma_f32_16x16x32_bf16(fab.f, whf.f, z, 0, 0, 0);
    D[4] = make_uint2(pk_rhu(d[0], d[1], sel), pk_rhu(d[2], d[3], sel));
}

// V-pass for one 16-row out-tile from D_prev (chunk t) + D_cur (chunk t+1).
__device__ __forceinline__ void vstep(const frag& whv,
                                      const uint2* __restrict__ Dp,
                                      const uint2* __restrict__ Dc,
                                      float& lsum)
{
    const f32x4 z = {0.f, 0.f, 0.f, 0.f};
    f32x4 res[5];
#pragma unroll
    for (int p = 0; p < 5; ++p) {
        frag Bf;
        Bf.u[0] = Dp[p].x; Bf.u[1] = Dp[p].y;
        Bf.u[2] = Dc[p].x; Bf.u[3] = Dc[p].y;
        res[p] = __builtin_amdgcn_mfma_f32_16x16x32_bf16(whv.f, Bf.f, z, 0, 0, 0);
    }
#pragma unroll
    for (int j = 0; j < 4; ++j) {
        const float mu1 = res[0][j];
        const float mu2 = res[1][j];
        const float m1s = mu1 * mu1;
        const float m2s = mu2 * mu2;
        const float m12 = mu1 * mu2;
        const float s11 = res[2][j] - m1s;
        const float s22 = res[3][j] - m2s;
        const float s12 = res[4][j] - m12;
        const float num = (2.f * m12 + C1c) * (2.f * s12 + C2c);
        const float den = (m1s + m2s + C1c) * (s11 + s22 + C2c);
        lsum = fmaf(num, __builtin_amdgcn_rcpf(den), lsum);
    }
}

__global__ __launch_bounds__(256, 3)
void ssim_mfma(const float* __restrict__ img1, const float* __restrict__ img2,
               const unsigned int* __restrict__ wbuf,
               float* __restrict__ partials)
{
    const int tid  = threadIdx.x;
    const int lane = tid & 63;
    const int wave = tid >> 6;        // 0..3
    const int ln   = lane & 15;
    const int lg   = lane >> 4;       // 0..3
    const int tx0w = blockIdx.x * TX + wave * 16;   // wave's 16 out-cols
    const int y0   = blockIdx.y * BY;
    const float* __restrict__ p1 = img1 + (size_t)blockIdx.z * (IMW * IMH);
    const float* __restrict__ p2 = img2 + (size_t)blockIdx.z * (IMW * IMH);
    const unsigned int sel = 0x07060302u;

    frag whf, whv;
    whf.q = reinterpret_cast<const uint4*>(wbuf)[lane * 2];
    whv.q = reinterpret_cast<const uint4*>(wbuf)[lane * 2 + 1];

    // Coalesced-load lane mapping + loop-invariant LDS indices.
    const int r  = lane >> 2;                  // 0..15 (row within chunk)
    const int jj = lane & 3;                   // 16B seg within 64B line
    const int cA = tx0w - 16;                  // aligned window base col
    // write: seg s of row r -> slot (s+r)&15 (uint4 idx within 256/img)
    const int wi0 = r * 16 + ((jj + 0 + r) & 15);
    const int wi1 = r * 16 + ((jj + 4 + r) & 15);
    const int wi2 = r * 16 + ((jj + 8 + r) & 15);
    // read: row ln, segs 2lg+2, 2lg+3 (= window cols 8lg..8lg+7)
    const int ri0 = ln * 16 + ((2 * lg + 2 + ln) & 15);
    const int ri1 = ln * 16 + ((2 * lg + 3 + ln) & 15);

    __shared__ float4 lds4[4][512];            // 8 KB per wave: 2 imgs x 4 KB
    float4* ldsW = &lds4[wave][0];

    float lsum = 0.f;

    // ---- Main march: 4-slot rotation, 3-chunk lookahead (v18 schedule).
    // Step c: load chunk c+3 into the slot freed at step c-1; stage slot
    // c%4 to LDS; H-pass from LDS; V-pass emits tile c-1.
    Chunk S0, S1, S2, S3;
    uint2 DA[5], DB[5];

    hload(p1, p2, y0, r, cA, jj, 0, S0);
    hload(p1, p2, y0, r, cA, jj, 1, S1);
    hload(p1, p2, y0, r, cA, jj, 2, S2);
    hload(p1, p2, y0, r, cA, jj, 3, S3);
    hstage(ldsW, wi0, wi1, wi2, S0);
    hprocL(whf, sel, ldsW, ri0, ri1, DA);      // D of chunk 0

    for (int u = 0; u < 4; ++u) {
        const int c0 = 4 * u;                  // steps c0+1 .. c0+4
        if (c0 + 4 <= NCH) hload(p1, p2, y0, r, cA, jj, c0 + 4, S0);
        hstage(ldsW, wi0, wi1, wi2, S1);
        hprocL(whf, sel, ldsW, ri0, ri1, DB);
        vstep(whv, DA, DB, lsum);

        if (c0 + 5 <= NCH) hload(p1, p2, y0, r, cA, jj, c0 + 5, S1);
        hstage(ldsW, wi0, wi1, wi2, S2);
        hprocL(whf, sel, ldsW, ri0, ri1, DA);
        vstep(whv, DB, DA, lsum);

        if (c0 + 6 <= NCH) hload(p1, p2, y0, r, cA, jj, c0 + 6, S2);
        hstage(ldsW, wi0, wi1, wi2, S3);
        hprocL(whf, sel, ldsW, ri0, ri1, DB);
        vstep(whv, DA, DB, lsum);

        if (c0 + 7 <= NCH) hload(p1, p2, y0, r, cA, jj, c0 + 7, S3);
        hstage(ldsW, wi0, wi1, wi2, S0);
        hprocL(whf, sel, ldsW, ri0, ri1, DA);
        vstep(whv, DB, DA, lsum);
    }

    // ---- Block reduction -> per-block partial ----
#pragma unroll
    for (int off = 32; off > 0; off >>= 1)
        lsum += __shfl_down(lsum, off, 64);

    __shared__ float wsum[4];
    if (lane == 0) wsum[wave] = lsum;
    __syncthreads();
    if (tid == 0) {
        float tot = wsum[0] + wsum[1] + wsum[2] + wsum[3];
        const int bid = (blockIdx.z * gridDim.y + blockIdx.y) * gridDim.x + blockIdx.x;
        partials[bid] = tot;
    }
}

__global__ __launch_bounds__(256)
void ssim_reduce_kernel(const float* __restrict__ partials,
                        float* __restrict__ out)
{
    __shared__ double sm[256];
    double s = 0.0;
    for (int i = threadIdx.x; i < NBLK; i += 256) s += (double)partials[i];
    sm[threadIdx.x] = s;
    __syncthreads();
    for (int stride = 128; stride > 0; stride >>= 1) {
        if (threadIdx.x < stride) sm[threadIdx.x] += sm[threadIdx.x + stride];
        __syncthreads();
    }
    if (threadIdx.x == 0) {
        double mean = sm[0] / (double)((size_t)NPL * IMW * IMH);
        out[0] = (float)(1.0 - mean);
    }
}

extern "C" void kernel_launch(void* const* d_in, const int* in_sizes, int n_in,
                              void* d_out, int out_size, void* d_ws, size_t ws_size,
                              hipStream_t stream)
{
    (void)in_sizes; (void)n_in; (void)out_size; (void)ws_size;
    const float* img1 = (const float*)d_in[0];
    const float* img2 = (const float*)d_in[1];
    float* out = (float*)d_out;

    unsigned int* wbuf = (unsigned int*)d_ws;              // 2 KB weight table
    float* partials = (float*)((char*)d_ws + 4096);        // NBLK floats

    ssim_weight_setup<<<1, 64, 0, stream>>>(wbuf);
    dim3 grid(GX, GYB, NPL);
    ssim_mfma<<<grid, 256, 0, stream>>>(img1, img2, wbuf, partials);
    ssim_reduce_kernel<<<1, 256, 0, stream>>>(partials, out);
}

// Round 8
// 44.720 us; speedup vs baseline: 2.0296x; 2.0296x over previous
//
#include <hip/hip_runtime.h>

// SSIM v20: block-cooperative coalesced staging through a double-buffered
// LDS ring. Evidence: every scattered-load variant (v12-v18) pinned at
// 1.73-1.85 TB/s regardless of TLP/ILP; v19's coalesced attempt reached
// 2.7 TB/s total HBM but died of register-array scratch demotion. v20:
// whole block loads chunk window [bx*64-16,+80) = 24 f4/row x 16 rows x
// 2 imgs = 768 f4 = 3 f4/thread (NAMED regs rA0..2/rB0..2 - no arrays,
// no spill surface) -> ds_write to 12KB chunk buffer (rotate swizzle
// slot=(seg+row)%24 -> 2-way read conflicts = free) -> fragment ds_read
// gives v14's exact floats -> identical pack/MFMA/vstep chain.
// Sync: raw s_barrier + manual lgkmcnt(0) (NOT __syncthreads - that
// drains vmcnt(0) and would serialize the 1-chunk-ahead prefetch).
// Compiler auto-inserts counted vmcnt before each ds_write (reads the
// load dest regs), so next chunk's loads stay in flight across barriers.
// OOB: clamped load addresses; zero-predicate applied after LDS read
// (same rowok/colok as v12) -> bit-identical, absmax exactly 0.0078125.

typedef __attribute__((ext_vector_type(8))) short bf16x8;
typedef __attribute__((ext_vector_type(4))) float f32x4;

constexpr int TX   = 64;             // block out-cols (4 waves x 16)
constexpr int BY   = 256;            // block out-rows
constexpr int IMW  = 512;
constexpr int IMH  = 512;
constexpr int NPL  = 48;
constexpr int GX   = IMW / TX;       // 8
constexpr int GYB  = IMH / BY;       // 2
constexpr int NBLK = GX * GYB * NPL; // 768
constexpr int NCH  = BY / 16;        // 16; chunks 0..16
constexpr int CB   = 12288;          // bytes per chunk buffer (768 float4)
constexpr float C1c = 0.01f * 0.01f;
constexpr float C2c = 0.03f * 0.03f;

union frag {
    bf16x8 f;
    unsigned int u[4];
    uint4 q;
};

// RNE f32->bf16 pair pack (setup kernel only).
__device__ __forceinline__ unsigned int pk_bf16(float lo, float hi) {
    unsigned int a = __float_as_uint(lo);
    unsigned int b = __float_as_uint(hi);
    a += 0x7FFFu + ((a >> 16) & 1u);
    b += 0x7FFFu + ((b >> 16) & 1u);
    return (b & 0xFFFF0000u) | (a >> 16);
}

// Fast pack: round-half-up + byte-perm merge (3 VALU ops per pair).
__device__ __forceinline__ unsigned int pk_rhu(float lo, float hi, unsigned sel) {
    unsigned int a = __float_as_uint(lo) + 0x8000u;
    unsigned int b = __float_as_uint(hi) + 0x8000u;
    unsigned int r;
    asm("v_perm_b32 %0, %1, %2, %3" : "=v"(r) : "v"(b), "v"(a), "s"(sel));
    return r;
}

// Normalized 11-tap Gaussian (sigma=1.5); wt[d] for d in [0,11), else 0.
__device__ __forceinline__ float wsel(int d) {
    float w = 0.f;
    w = (d == 0 || d == 10) ? 0.00102838f : w;
    w = (d == 1 || d == 9)  ? 0.00759876f : w;
    w = (d == 2 || d == 8)  ? 0.03600077f : w;
    w = (d == 3 || d == 7)  ? 0.10936082f : w;
    w = (d == 4 || d == 6)  ? 0.21300553f : w;
    w = (d == 5)            ? 0.26601171f : w;
    return w;
}

// Per-lane weight fragments (8 words/lane):
//   words 0..3: whf  — H-pass B-frag,  W[k][n] = wt[k-n-3],   k = lg*8+j
//   words 4..7: whv  — V-pass A-frag with permuted rows,
//                      W'[k][n] = wt[wr(k)-n-3],
//                      wr(k) = (j<4 ? lg*4+j : 12+lg*4+j), j = k&7
__global__ void ssim_weight_setup(unsigned int* __restrict__ wbuf)
{
    const int lane = threadIdx.x & 63;
    const int ln   = lane & 15;
    const int lg   = lane >> 4;
#pragma unroll
    for (int w = 0; w < 4; ++w) {
        const int ka = lg * 8 + 2 * w;
        wbuf[lane * 8 + w] = pk_bf16(wsel(ka - ln - 3), wsel(ka + 1 - ln - 3));
        const int j0  = 2 * w;
        const int wr0 = (j0 < 4) ? (lg * 4 + j0) : (12 + lg * 4 + j0);
        wbuf[lane * 8 + 4 + w] = pk_bf16(wsel(wr0 - ln - 3), wsel(wr0 + 1 - ln - 3));
    }
}

// Clamped coalesced float4 load (OOB rows/cols fetch valid garbage that is
// zeroed at the fragment stage -- never fed into the math).
__device__ __forceinline__ float4 ldf4(const float* __restrict__ gb, int ir, int colc)
{
    ir = ir < 0 ? 0 : (ir > IMH - 1 ? IMH - 1 : ir);
    return *reinterpret_cast<const float4*>(gb + (size_t)ir * IMW + colc);
}

// H-pass for one chunk from LDS: read 2 f4/img (= v12's 8 fragment floats),
// zero-predicate, pack, 5 MFMAs -> packed D (uint2 per plane).
template<int OFF>
__device__ __forceinline__ void cstep(const char* lds, int ro0, int ro1, bool ok,
                                      const frag& whf, unsigned sel,
                                      uint2* __restrict__ D)
{
    float4 ra0 = *reinterpret_cast<const float4*>(lds + OFF + ro0);
    float4 ra1 = *reinterpret_cast<const float4*>(lds + OFF + ro1);
    float4 rb0 = *reinterpret_cast<const float4*>(lds + OFF + CB / 2 + ro0);
    float4 rb1 = *reinterpret_cast<const float4*>(lds + OFF + CB / 2 + ro1);
    const float4 zz = make_float4(0.f, 0.f, 0.f, 0.f);
    if (!ok) { ra0 = zz; ra1 = zz; rb0 = zz; rb1 = zz; }

    const f32x4 z = {0.f, 0.f, 0.f, 0.f};
    frag fa, fb, faa, fbb, fab;
    fa.u[0]  = pk_rhu(ra0.x, ra0.y, sel);          fb.u[0]  = pk_rhu(rb0.x, rb0.y, sel);
    faa.u[0] = pk_rhu(ra0.x*ra0.x, ra0.y*ra0.y, sel);
    fbb.u[0] = pk_rhu(rb0.x*rb0.x, rb0.y*rb0.y, sel);
    fab.u[0] = pk_rhu(ra0.x*rb0.x, ra0.y*rb0.y, sel);
    fa.u[1]  = pk_rhu(ra0.z, ra0.w, sel);          fb.u[1]  = pk_rhu(rb0.z, rb0.w, sel);
    faa.u[1] = pk_rhu(ra0.z*ra0.z, ra0.w*ra0.w, sel);
    fbb.u[1] = pk_rhu(rb0.z*rb0.z, rb0.w*rb0.w, sel);
    fab.u[1] = pk_rhu(ra0.z*rb0.z, ra0.w*rb0.w, sel);
    fa.u[2]  = pk_rhu(ra1.x, ra1.y, sel);          fb.u[2]  = pk_rhu(rb1.x, rb1.y, sel);
    faa.u[2] = pk_rhu(ra1.x*ra1.x, ra1.y*ra1.y, sel);
    fbb.u[2] = pk_rhu(rb1.x*rb1.x, rb1.y*rb1.y, sel);
    fab.u[2] = pk_rhu(ra1.x*rb1.x, ra1.y*rb1.y, sel);
    fa.u[3]  = pk_rhu(ra1.z, ra1.w, sel);          fb.u[3]  = pk_rhu(rb1.z, rb1.w, sel);
    faa.u[3] = pk_rhu(ra1.z*ra1.z, ra1.w*ra1.w, sel);
    fbb.u[3] = pk_rhu(rb1.z*rb1.z, rb1.w*rb1.w, sel);
    fab.u[3] = pk_rhu(ra1.z*rb1.z, ra1.w*rb1.w, sel);

    f32x4 d;
    d = __builtin_amdgcn_mfma_f32_16x16x32_bf16(fa.f,  whf.f, z, 0, 0, 0);
    D[0] = make_uint2(pk_rhu(d[0], d[1], sel), pk_rhu(d[2], d[3], sel));
    d = __builtin_amdgcn_mfma_f32_16x16x32_bf16(fb.f,  whf.f, z, 0, 0, 0);
    D[1] = make_uint2(pk_rhu(d[0], d[1], sel), pk_rhu(d[2], d[3], sel));
    d = __builtin_amdgcn_mfma_f32_16x16x32_bf16(faa.f, whf.f, z, 0, 0, 0);
    D[2] = make_uint2(pk_rhu(d[0], d[1], sel), pk_rhu(d[2], d[3], sel));
    d = __builtin_amdgcn_mfma_f32_16x16x32_bf16(fbb.f, whf.f, z, 0, 0, 0);
    D[3] = make_uint2(pk_rhu(d[0], d[1], sel), pk_rhu(d[2], d[3], sel));
    d = __builtin_amdgcn_mfma_f32_16x16x32_bf16(fab.f, whf.f, z, 0, 0, 0);
    D[4] = make_uint2(pk_rhu(d[0], d[1], sel), pk_rhu(d[2], d[3], sel));
}

// V-pass for one 16-row out-tile from D_prev (chunk t) + D_cur (chunk t+1).
__device__ __forceinline__ void vstep(const frag& whv,
                                      const uint2* __restrict__ Dp,
                                      const uint2* __restrict__ Dc,
                                      float& lsum)
{
    const f32x4 z = {0.f, 0.f, 0.f, 0.f};
    f32x4 res[5];
#pragma unroll
    for (int p = 0; p < 5; ++p) {
        frag Bf;
        Bf.u[0] = Dp[p].x; Bf.u[1] = Dp[p].y;
        Bf.u[2] = Dc[p].x; Bf.u[3] = Dc[p].y;
        res[p] = __builtin_amdgcn_mfma_f32_16x16x32_bf16(whv.f, Bf.f, z, 0, 0, 0);
    }
#pragma unroll
    for (int j = 0; j < 4; ++j) {
        const float mu1 = res[0][j];
        const float mu2 = res[1][j];
        const float m1s = mu1 * mu1;
        const float m2s = mu2 * mu2;
        const float m12 = mu1 * mu2;
        const float s11 = res[2][j] - m1s;
        const float s22 = res[3][j] - m2s;
        const float s12 = res[4][j] - m12;
        const float num = (2.f * m12 + C1c) * (2.f * s12 + C2c);
        const float den = (m1s + m2s + C1c) * (s11 + s22 + C2c);
        lsum = fmaf(num, __builtin_amdgcn_rcpf(den), lsum);
    }
}

__global__ __launch_bounds__(256, 3)
void ssim_mfma(const float* __restrict__ img1, const float* __restrict__ img2,
               const unsigned int* __restrict__ wbuf,
               float* __restrict__ partials)
{
    const int tid  = threadIdx.x;
    const int lane = tid & 63;
    const int wave = tid >> 6;        // 0..3
    const int ln   = lane & 15;
    const int lg   = lane >> 4;       // 0..3
    const int bx   = blockIdx.x;
    const int y0   = blockIdx.y * BY;
    const float* __restrict__ p1 = img1 + (size_t)blockIdx.z * (IMW * IMH);
    const float* __restrict__ p2 = img2 + (size_t)blockIdx.z * (IMW * IMH);
    const unsigned int sel = 0x07060302u;

    frag whf, whv;
    whf.q = reinterpret_cast<const uint4*>(wbuf)[lane * 2];
    whv.q = reinterpret_cast<const uint4*>(wbuf)[lane * 2 + 1];

    __shared__ __align__(16) char lds[2 * CB];
    __shared__ float wsum[4];

    // ---- per-thread load-slot constants (3 slots: L = tid, tid+256, tid+512)
    // within-img index Lp = L%384; row = Lp/24; slot k = Lp%24 holds global
    // seg (k-row)%24 of window col = bx*64-16+4*seg (rotate swizzle).
    const int Lp0 = tid;                       // L0 < 384 -> img1
    const int rw0 = Lp0 / 24;
    int sg0 = (Lp0 % 24) - rw0; sg0 += (sg0 < 0) ? 24 : 0;
    int cc0 = bx * TX - 16 + 4 * sg0; cc0 = cc0 < 0 ? 0 : (cc0 > IMW - 4 ? IMW - 4 : cc0);
    const float* gb0 = p1;
    const int wo0 = tid * 16;

    const int L1  = tid + 256;
    const int Lp1 = (L1 < 384) ? L1 : (L1 - 384);
    const int rw1 = Lp1 / 24;
    int sg1 = (Lp1 % 24) - rw1; sg1 += (sg1 < 0) ? 24 : 0;
    int cc1 = bx * TX - 16 + 4 * sg1; cc1 = cc1 < 0 ? 0 : (cc1 > IMW - 4 ? IMW - 4 : cc1);
    const float* gb1 = (L1 < 384) ? p1 : p2;
    const int wo1 = L1 * 16;

    const int L2  = tid + 512;                 // >= 512 -> img2
    const int Lp2 = L2 - 384;
    const int rw2 = Lp2 / 24;
    int sg2 = (Lp2 % 24) - rw2; sg2 += (sg2 < 0) ? 24 : 0;
    int cc2 = bx * TX - 16 + 4 * sg2; cc2 = cc2 < 0 ? 0 : (cc2 > IMW - 4 ? IMW - 4 : cc2);
    const float* gb2 = p2;
    const int wo2 = L2 * 16;

    // ---- fragment read offsets (loop-invariant): row ln, segs s0, s0+1
    const int s0  = 4 * wave + 2 + 2 * lg;
    const int rk0 = (s0 + ln) % 24;
    const int rk1 = (s0 + 1 + ln) % 24;
    const int ro0 = (ln * 24 + rk0) * 16;
    const int ro1 = (ln * 24 + rk1) * 16;
    const int cbase = bx * TX + wave * 16 - 8 + lg * 8;
    const bool colok = ((unsigned)cbase <= (unsigned)(IMW - 8));

    float4 rA0, rA1, rA2, rB0, rB1, rB2;
    uint2 DA[5], DB[5];
    float lsum = 0.f;

#define LOADC(c, X0, X1, X2) do{ \
    X0 = ldf4(gb0, y0 + 16 * (c) - 8 + rw0, cc0); \
    X1 = ldf4(gb1, y0 + 16 * (c) - 8 + rw1, cc1); \
    X2 = ldf4(gb2, y0 + 16 * (c) - 8 + rw2, cc2); } while (0)
#define WRC(OFF, X0, X1, X2) do{ \
    *reinterpret_cast<float4*>(lds + (OFF) + wo0) = X0; \
    *reinterpret_cast<float4*>(lds + (OFF) + wo1) = X1; \
    *reinterpret_cast<float4*>(lds + (OFF) + wo2) = X2; } while (0)
#define BAR() do{ \
    asm volatile("s_waitcnt lgkmcnt(0)" ::: "memory"); \
    __builtin_amdgcn_sched_barrier(0); \
    __builtin_amdgcn_s_barrier(); \
    __builtin_amdgcn_sched_barrier(0); } while (0)
#define ROWOK(c) (colok && ((unsigned)(y0 + 16 * (c) - 8 + ln) < (unsigned)IMH))

    // ---- prologue: buf0=chunk0, buf1=chunk1, chunk2 in flight in rA
    LOADC(0, rA0, rA1, rA2);
    LOADC(1, rB0, rB1, rB2);
    WRC(0, rA0, rA1, rA2);                 // auto counted-vmcnt wait on rA
    BAR();                                 // buf0 ready
    LOADC(2, rA0, rA1, rA2);
    WRC(CB, rB0, rB1, rB2);                // waits rB only; chunk2 stays in flight
    cstep<0>(lds, ro0, ro1, ROWOK(0), whf, sel, DA);   // H of chunk 0
    BAR();                                 // buf1 ready

    // ---- main march: steps c=1..16, double-buffer ping-pong, 1 barrier/step
    for (int u = 0; u < 8; ++u) {
        const int c = 2 * u + 1;
        if (c + 2 <= NCH) LOADC(c + 2, rB0, rB1, rB2);
        WRC(0, rA0, rA1, rA2);             // chunk c+1 -> buf0
        cstep<CB>(lds, ro0, ro1, ROWOK(c), whf, sel, DB);  // chunk c
        vstep(whv, DA, DB, lsum);          // tile c-1
        BAR();
        if (c + 3 <= NCH) LOADC(c + 3, rA0, rA1, rA2);
        if (c + 2 <= NCH) WRC(CB, rB0, rB1, rB2);          // chunk c+2 -> buf1
        cstep<0>(lds, ro0, ro1, ROWOK(c + 1), whf, sel, DA); // chunk c+1
        vstep(whv, DB, DA, lsum);          // tile c
        BAR();
    }
#undef LOADC
#undef WRC
#undef BAR
#undef ROWOK

    // ---- Block reduction -> per-block partial ----
#pragma unroll
    for (int off = 32; off > 0; off >>= 1)
        lsum += __shfl_down(lsum, off, 64);

    if (lane == 0) wsum[wave] = lsum;
    __syncthreads();
    if (tid == 0) {
        float tot = wsum[0] + wsum[1] + wsum[2] + wsum[3];
        const int bid = (blockIdx.z * gridDim.y + blockIdx.y) * gridDim.x + blockIdx.x;
        partials[bid] = tot;
    }
}

__global__ __launch_bounds__(256)
void ssim_reduce_kernel(const float* __restrict__ partials,
                        float* __restrict__ out)
{
    __shared__ double sm[256];
    double s = 0.0;
    for (int i = threadIdx.x; i < NBLK; i += 256) s += (double)partials[i];
    sm[threadIdx.x] = s;
    __syncthreads();
    for (int stride = 128; stride > 0; stride >>= 1) {
        if (threadIdx.x < stride) sm[threadIdx.x] += sm[threadIdx.x + stride];
        __syncthreads();
    }
    if (threadIdx.x == 0) {
        double mean = sm[0] / (double)((size_t)NPL * IMW * IMH);
        out[0] = (float)(1.0 - mean);
    }
}

extern "C" void kernel_launch(void* const* d_in, const int* in_sizes, int n_in,
                              void* d_out, int out_size, void* d_ws, size_t ws_size,
                              hipStream_t stream)
{
    (void)in_sizes; (void)n_in; (void)out_size; (void)ws_size;
    const float* img1 = (const float*)d_in[0];
    const float* img2 = (const float*)d_in[1];
    float* out = (float*)d_out;

    unsigned int* wbuf = (unsigned int*)d_ws;              // 2 KB weight table
    float* partials = (float*)((char*)d_ws + 4096);        // NBLK floats

    ssim_weight_setup<<<1, 64, 0, stream>>>(wbuf);
    dim3 grid(GX, GYB, NPL);
    ssim_mfma<<<grid, 256, 0, stream>>>(img1, img2, wbuf, partials);
    ssim_reduce_kernel<<<1, 256, 0, stream>>>(partials, out);
}